// Round 8
// baseline (154.110 us; speedup 1.0000x reference)
//
#include <hip/hip_runtime.h>
#include <hip/hip_fp16.h>
#include <math.h>

// Problem constants (B=2, T=8, N=128 -> S=1024, Hd=64, H=8)
#define S_TOK 1024

// e3nn 'integral' normalization constants
#define C0_F  0.28209479177387814f   // 0.5/sqrt(pi)
#define C1_F  0.4886025119029199f    // sqrt(3/(4pi))
#define C2_F  0.6307831305050401f    // sqrt(5/(4pi))
#define C2S3  1.0925484305920792f    // C2*sqrt(3)
#define C2H3  0.5462742152960396f    // C2*sqrt(3)/2

// ws / LDS constant-region layout (bytes). Fragment-major fp16: [tile][lane][4 f16]
#define W1_OFF  0        // 4*64*8  = 2048
#define W2_OFF  2048     // 16*64*8 = 8192
#define W3_OFF  10240    // 4*64*8  = 2048
#define B1P_OFF 12288    // 64 f32 (b1 + C0*W1[0,:])
#define B2_OFF  12544    // 64 f32
#define B3P_OFF 12800    // 16 f32 (b3 padded with zeros)
#define CONST_BYTES 12864            // = 804 * 16
// per-wave 2048B region: sh rows as f16 (24B stride, 1536B used),
// reused as epilogue [8][64] f32 (2048B)
#define SH_OFF  12864
#define LDS_BYTES (CONST_BYTES + 4*2048)   // 21056

typedef __attribute__((ext_vector_type(4))) _Float16 half4v;   // 4 f16 (2 VGPR)
typedef __attribute__((ext_vector_type(2))) unsigned int uint2v;
typedef __attribute__((ext_vector_type(4))) float  f32x4;
typedef __attribute__((ext_vector_type(4))) unsigned int u32x4;

// ---------- helpers ----------
__device__ __forceinline__ f32x4 mfma16h(half4v a, half4v b, f32x4 c) {
    return __builtin_amdgcn_mfma_f32_16x16x16f16(a, b, c, 0, 0, 0);
}

// f32x4 -> 4 packed fp16 via v_cvt_pkrtz_f16_f32 (2 ops total)
__device__ __forceinline__ half4v cvt4(f32x4 v) {
    uint2v t;
    t.x = __builtin_bit_cast(unsigned, __builtin_amdgcn_cvt_pkrtz(v.x, v.y));
    t.y = __builtin_bit_cast(unsigned, __builtin_amdgcn_cvt_pkrtz(v.z, v.w));
    return __builtin_bit_cast(half4v, t);
}

// packed-f16 silu on 2 values: pk_mul, 2x v_exp_f16, pk_add, 2x v_rcp_f16, pk_mul
// x <= -12: exp2 -> inf -> rcp -> 0 -> out 0 (correct limit); x >> 0: out = x.
__device__ __forceinline__ unsigned silu_pk(unsigned xu) {
    const __half2 NL2E = __float2half2_rn(-1.442695041f);
    const __half2 ONE2 = __float2half2_rn(1.0f);
    __half2 x = __builtin_bit_cast(__half2, xu);
    __half2 t = h2exp2(__hmul2(x, NL2E));
    __half2 s = h2rcp(__hadd2(t, ONE2));
    return __builtin_bit_cast(unsigned, __hmul2(x, s));
}
// f32x4 preact -> f16 -> packed silu -> B-fragment
__device__ __forceinline__ half4v silucvt(f32x4 v) {
    uint2v u;
    u.x = silu_pk(__builtin_bit_cast(unsigned, __builtin_amdgcn_cvt_pkrtz(v.x, v.y)));
    u.y = silu_pk(__builtin_bit_cast(unsigned, __builtin_amdgcn_cvt_pkrtz(v.z, v.w)));
    return __builtin_bit_cast(half4v, u);
}

// ---------- prologue: stage weights into fragment-major fp16 layout in ws ----------
__global__ __launch_bounds__(256) void shab_stage(
    const float* __restrict__ w1, const float* __restrict__ b1,
    const float* __restrict__ w2, const float* __restrict__ b2,
    const float* __restrict__ w3, const float* __restrict__ b3,
    unsigned char* __restrict__ ws)
{
    const int gid = blockIdx.x * 256 + threadIdx.x;
    const int gstride = gridDim.x * 256;

    // W2^T frags: A[m][k]: m=ch2=mi*16+(lane&15), k=ch1=ks*16+4*(lane>>4)+i
    for (int idx = gid; idx < 16 * 64 * 4; idx += gstride) {
        const int tile = idx >> 8, lane = (idx >> 2) & 63, i = idx & 3;
        const int mi = tile >> 2, ks = tile & 3;
        const int ch2 = mi * 16 + (lane & 15);
        const int ch1 = ks * 16 + (lane >> 4) * 4 + i;
        ((_Float16*)(ws + W2_OFF))[idx] = (_Float16)w2[ch1 * 64 + ch2];   // RNE
    }
    // W1^T frags (sh index shifted by 1; k>=8 zero-padded): m=ch, k -> W1[k+1][ch]
    for (int idx = gid; idx < 4 * 64 * 4; idx += gstride) {
        const int tile = idx >> 8, lane = (idx >> 2) & 63, i = idx & 3;
        const int ch = tile * 16 + (lane & 15);
        const int k = (lane >> 4) * 4 + i;
        const float v = (k < 8) ? w1[(k + 1) * 64 + ch] : 0.f;
        ((_Float16*)(ws + W1_OFF))[idx] = (_Float16)v;
    }
    // W3^T frags (heads padded 8->16): m=head, k=ch2 -> W3[ch2][head]
    for (int idx = gid; idx < 4 * 64 * 4; idx += gstride) {
        const int ks = idx >> 8, lane = (idx >> 2) & 63, i = idx & 3;
        const int head = lane & 15;
        const int ch2 = ks * 16 + (lane >> 4) * 4 + i;
        const float v = (head < 8) ? w3[ch2 * 8 + head] : 0.f;
        ((_Float16*)(ws + W3_OFF))[idx] = (_Float16)v;
    }
    if (gid < 64) {
        ((float*)(ws + B1P_OFF))[gid] = b1[gid] + C0_F * w1[gid];  // fold sh[0]=C0 row
        ((float*)(ws + B2_OFF))[gid]  = b2[gid];
    }
    if (gid < 16) ((float*)(ws + B3P_OFF))[gid] = (gid < 8) ? b3[gid] : 0.f;
}

// ---------- main kernel ----------
__global__ __launch_bounds__(256, 7) void shab_mfma(
    const float* __restrict__ coords, const unsigned char* __restrict__ ws,
    float* __restrict__ out)
{
    __shared__ __align__(16) unsigned char lds[LDS_BYTES];
    const int tid = threadIdx.x;
    const int wave = tid >> 6, lane = tid & 63, g = lane >> 4, p = lane & 15;

    // stage constants ws -> LDS (12864B = 804 x 16B)
    {
        const u32x4* src = (const u32x4*)ws;
        u32x4* dst = (u32x4*)lds;
        #pragma unroll
        for (int k = 0; k < 4; ++k) { int o = tid + k * 256; if (o < 804) dst[o] = src[o]; }
    }

    const int bid = blockIdx.x;
    const int b = bid >> 12, rem = bid & 4095;
    const int irow = rem >> 2, jt = rem & 3;
    const int j = jt * 256 + wave * 64 + lane;

    // ---- spherical harmonics (per-lane pair: (irow, j)) ----
    // Reference's two-step normalize == rel/||rel|| (zero stays zero).
    const float* cb = coords + (size_t)b * 3 * S_TOK;
    const float xi = cb[irow * 3 + 0], yi = cb[irow * 3 + 1], zi = cb[irow * 3 + 2];
    const float xj = cb[j * 3 + 0],    yj = cb[j * 3 + 1],    zj = cb[j * 3 + 2];
    const float rx = xi - xj, ry = yi - yj, rz = zi - zj;
    const float n2 = rx * rx + ry * ry + rz * rz;
    const float inv = (n2 > 0.f) ? __builtin_amdgcn_rsqf(n2) : 0.f;
    const float x = rx * inv, y = ry * inv, z = rz * inv;

    f32x4 s0, s1;             // sh[1..4], sh[5..8]  (sh[0]=C0 folded into bias1)
    s0.x = C1_F * x; s0.y = C1_F * y; s0.z = C1_F * z; s0.w = C2S3 * x * z;
    s1.x = C2S3 * x * y;
    s1.y = C2_F * (y * y - 0.5f * (x * x + z * z));
    s1.z = C2S3 * y * z;
    s1.w = C2H3 * (z * z - x * x);

    // store sh as f16 (B-frag-ready): row stride 24B, two b64 writes
    char* shbase = (char*)lds + SH_OFF + wave * 2048;
    {
        uint2v uA = __builtin_bit_cast(uint2v, cvt4(s0));
        uint2v uB = __builtin_bit_cast(uint2v, cvt4(s1));
        *(uint2v*)(shbase + lane * 24)     = uA;
        *(uint2v*)(shbase + lane * 24 + 8) = uB;
    }
    __syncthreads();   // covers const-copy AND sh redistribution

    // ---- layer 1 (fused silu+pack: d1 never materializes as an array) ----
    // h1^T[ch][pair] = W1^T . sh^T + b1'  (K=16, k>=8 zero in A)
    half4v a1[4]; f32x4 bias1[4];
    #pragma unroll
    for (int mi = 0; mi < 4; ++mi) {
        a1[mi]    = *(const half4v*)((char*)lds + W1_OFF + (mi * 64 + lane) * 8);
        bias1[mi] = *(const f32x4*)((char*)lds + B1P_OFF + (mi * 16 + 4 * g) * 4);
    }
    half4v b2f[4][4];          // layer-2 B-frags (only 32 VGPRs live)
    #pragma unroll
    for (int ni = 0; ni < 4; ++ni) {
        // B-frag: lane holds f16 sh[4(g&1)+1 .. +4] of pair ni*16+p (g>=2: A is zero)
        half4v bf = *(const half4v*)(shbase + (ni * 16 + p) * 24 + (g & 1) * 8);
        #pragma unroll
        for (int mi = 0; mi < 4; ++mi) {
            f32x4 acc = mfma16h(a1[mi], bf, bias1[mi]);
            b2f[mi][ni] = silucvt(acc);            // D1(mi,ni) -> B2-frag(ks=mi,ni)
        }
    }

    // ---- layer 2 with layer-3 accumulation fused into the mi loop ----
    half4v a3[4];
    #pragma unroll
    for (int ks = 0; ks < 4; ++ks)
        a3[ks] = *(const half4v*)((char*)lds + W3_OFF + (ks * 64 + lane) * 8);
    const f32x4 bias3v = *(const f32x4*)((char*)lds + B3P_OFF + 4 * g * 4);
    f32x4 acc3[4];
    #pragma unroll
    for (int ni = 0; ni < 4; ++ni) acc3[ni] = bias3v;

    #pragma unroll
    for (int mi = 0; mi < 4; ++mi) {
        half4v a2[4];
        #pragma unroll
        for (int ks = 0; ks < 4; ++ks)
            a2[ks] = *(const half4v*)((char*)lds + W2_OFF + ((mi * 4 + ks) * 64 + lane) * 8);
        const f32x4 bias2v = *(const f32x4*)((char*)lds + B2_OFF + (mi * 16 + 4 * g) * 4);
        #pragma unroll
        for (int ni = 0; ni < 4; ++ni) {
            f32x4 acc = bias2v;
            #pragma unroll
            for (int ks = 0; ks < 4; ++ks)
                acc = mfma16h(a2[ks], b2f[ks][ni], acc);
            half4v b3 = silucvt(acc);              // D2(mi,ni) -> B3-frag(ks=mi,ni)
            acc3[ni] = mfma16h(a3[mi], b3, acc3[ni]);
        }
    }

    // ---- epilogue: transpose via LDS (reuse sh region) for coalesced 256B stores ----
    __syncthreads();   // everyone done reading sh region (it was layer-1 input)
    if (g < 2) {
        #pragma unroll
        for (int ni = 0; ni < 4; ++ni) {
            #pragma unroll
            for (int i2 = 0; i2 < 4; ++i2)
                *(float*)(shbase + (4 * g + i2) * 256 + (ni * 16 + p) * 4) = acc3[ni][i2];
        }
    }
    __syncthreads();
    #pragma unroll
    for (int s = 0; s < 8; ++s) {
        const float v = *(const float*)(shbase + s * 256 + lane * 4);
        out[((size_t)(b * 8 + s) << 20) + ((size_t)irow << 10) + j] = v;
    }
}

extern "C" void kernel_launch(void* const* d_in, const int* in_sizes, int n_in,
                              void* d_out, int out_size, void* d_ws, size_t ws_size,
                              hipStream_t stream)
{
    const float* coords = (const float*)d_in[0];
    const float* w1 = (const float*)d_in[1];
    const float* b1 = (const float*)d_in[2];
    const float* w2 = (const float*)d_in[3];
    const float* b2 = (const float*)d_in[4];
    const float* w3 = (const float*)d_in[5];
    const float* b3 = (const float*)d_in[6];
    float* out = (float*)d_out;

    shab_stage<<<16, 256, 0, stream>>>(w1, b1, w2, b2, w3, b3, (unsigned char*)d_ws);

    const int B = in_sizes[0] / (S_TOK * 3);   // = 2
    shab_mfma<<<dim3(B * S_TOK * 4), 256, 0, stream>>>(coords, (const unsigned char*)d_ws, out);
}

// Round 9
// 145.432 us; speedup vs baseline: 1.0597x; 1.0597x over previous
//
#include <hip/hip_runtime.h>
#include <hip/hip_fp16.h>
#include <math.h>

// Problem constants (B=2, T=8, N=128 -> S=1024, Hd=64, H=8)
#define S_TOK 1024

// e3nn 'integral' normalization constants
#define C0_F  0.28209479177387814f   // 0.5/sqrt(pi)
#define C1_F  0.4886025119029199f    // sqrt(3/(4pi))
#define C2_F  0.6307831305050401f    // sqrt(5/(4pi))
#define C2S3  1.0925484305920792f    // C2*sqrt(3)
#define C2H3  0.5462742152960396f    // C2*sqrt(3)/2

// ws / LDS constant-region layout (bytes). Fragment-major fp16: [tile][lane][4 f16]
#define W1_OFF  0        // 4*64*8  = 2048
#define W2_OFF  2048     // 16*64*8 = 8192
#define W3_OFF  10240    // 4*64*8  = 2048
#define B1P_OFF 12288    // 64 f32 (b1 + C0*W1[0,:])
#define B2_OFF  12544    // 64 f32
#define B3P_OFF 12800    // 16 f32 (b3 padded with zeros)
#define CONST_BYTES 12864            // = 804 * 16
// per-wave 2048B region: sh rows as f16 (24B stride, 1536B used),
// reused as epilogue [8][64] f32 (2048B)
#define SH_OFF  12864
#define LDS_BYTES (CONST_BYTES + 4*2048)   // 21056

typedef __attribute__((ext_vector_type(4))) _Float16 half4v;   // 4 f16 (2 VGPR)
typedef __attribute__((ext_vector_type(2))) unsigned int uint2v;
typedef __attribute__((ext_vector_type(4))) float  f32x4;
typedef __attribute__((ext_vector_type(4))) unsigned int u32x4;

// ---------- helpers ----------
__device__ __forceinline__ f32x4 mfma16h(half4v a, half4v b, f32x4 c) {
    return __builtin_amdgcn_mfma_f32_16x16x16f16(a, b, c, 0, 0, 0);
}

// f32x4 -> 4 packed fp16 via v_cvt_pkrtz_f16_f32 (2 ops total)
__device__ __forceinline__ half4v cvt4(f32x4 v) {
    uint2v t;
    t.x = __builtin_bit_cast(unsigned, __builtin_amdgcn_cvt_pkrtz(v.x, v.y));
    t.y = __builtin_bit_cast(unsigned, __builtin_amdgcn_cvt_pkrtz(v.z, v.w));
    return __builtin_bit_cast(half4v, t);
}

// packed-f16 silu on 2 values: pk_mul, 2x v_exp_f16, pk_add, 2x v_rcp_f16, pk_mul
// x <= -12: exp2 -> inf -> rcp -> 0 -> out 0 (correct limit); x >> 0: out = x.
__device__ __forceinline__ unsigned silu_pk(unsigned xu) {
    const __half2 NL2E = __float2half2_rn(-1.442695041f);
    const __half2 ONE2 = __float2half2_rn(1.0f);
    __half2 x = __builtin_bit_cast(__half2, xu);
    __half2 t = h2exp2(__hmul2(x, NL2E));
    __half2 s = h2rcp(__hadd2(t, ONE2));
    return __builtin_bit_cast(unsigned, __hmul2(x, s));
}
// f32x4 preact -> f16 -> packed silu -> B-fragment
__device__ __forceinline__ half4v silucvt(f32x4 v) {
    uint2v u;
    u.x = silu_pk(__builtin_bit_cast(unsigned, __builtin_amdgcn_cvt_pkrtz(v.x, v.y)));
    u.y = silu_pk(__builtin_bit_cast(unsigned, __builtin_amdgcn_cvt_pkrtz(v.z, v.w)));
    return __builtin_bit_cast(half4v, u);
}

// ---------- prologue: stage weights into fragment-major fp16 layout in ws ----------
__global__ __launch_bounds__(256) void shab_stage(
    const float* __restrict__ w1, const float* __restrict__ b1,
    const float* __restrict__ w2, const float* __restrict__ b2,
    const float* __restrict__ w3, const float* __restrict__ b3,
    unsigned char* __restrict__ ws)
{
    const int gid = blockIdx.x * 256 + threadIdx.x;
    const int gstride = gridDim.x * 256;

    // W2^T frags: A[m][k]: m=ch2=mi*16+(lane&15), k=ch1=ks*16+4*(lane>>4)+i
    for (int idx = gid; idx < 16 * 64 * 4; idx += gstride) {
        const int tile = idx >> 8, lane = (idx >> 2) & 63, i = idx & 3;
        const int mi = tile >> 2, ks = tile & 3;
        const int ch2 = mi * 16 + (lane & 15);
        const int ch1 = ks * 16 + (lane >> 4) * 4 + i;
        ((_Float16*)(ws + W2_OFF))[idx] = (_Float16)w2[ch1 * 64 + ch2];   // RNE
    }
    // W1^T frags (sh index shifted by 1; k>=8 zero-padded): m=ch, k -> W1[k+1][ch]
    for (int idx = gid; idx < 4 * 64 * 4; idx += gstride) {
        const int tile = idx >> 8, lane = (idx >> 2) & 63, i = idx & 3;
        const int ch = tile * 16 + (lane & 15);
        const int k = (lane >> 4) * 4 + i;
        const float v = (k < 8) ? w1[(k + 1) * 64 + ch] : 0.f;
        ((_Float16*)(ws + W1_OFF))[idx] = (_Float16)v;
    }
    // W3^T frags (heads padded 8->16): m=head, k=ch2 -> W3[ch2][head]
    for (int idx = gid; idx < 4 * 64 * 4; idx += gstride) {
        const int ks = idx >> 8, lane = (idx >> 2) & 63, i = idx & 3;
        const int head = lane & 15;
        const int ch2 = ks * 16 + (lane >> 4) * 4 + i;
        const float v = (head < 8) ? w3[ch2 * 8 + head] : 0.f;
        ((_Float16*)(ws + W3_OFF))[idx] = (_Float16)v;
    }
    if (gid < 64) {
        ((float*)(ws + B1P_OFF))[gid] = b1[gid] + C0_F * w1[gid];  // fold sh[0]=C0 row
        ((float*)(ws + B2_OFF))[gid]  = b2[gid];
    }
    if (gid < 16) ((float*)(ws + B3P_OFF))[gid] = (gid < 8) ? b3[gid] : 0.f;
}

// ---------- main kernel: each block does 2 j-tiles of 256 pairs ----------
__global__ __launch_bounds__(256, 5) void shab_mfma(
    const float* __restrict__ coords, const unsigned char* __restrict__ ws,
    float* __restrict__ out)
{
    __shared__ __align__(16) unsigned char lds[LDS_BYTES];
    const int tid = threadIdx.x;
    const int wave = tid >> 6, lane = tid & 63, g = lane >> 4, p = lane & 15;

    // stage constants ws -> LDS (12864B = 804 x 16B) — once per block
    {
        const u32x4* src = (const u32x4*)ws;
        u32x4* dst = (u32x4*)lds;
        #pragma unroll
        for (int k = 0; k < 4; ++k) { int o = tid + k * 256; if (o < 804) dst[o] = src[o]; }
    }

    // grid: B * S_TOK * 2; block -> (b, irow, j-half of 512)
    const int bid = blockIdx.x;
    const int b = bid >> 11, rem = bid & 2047;
    const int irow = rem >> 1, jh = rem & 1;

    const float* cb = coords + (size_t)b * 3 * S_TOK;
    const float xi = cb[irow * 3 + 0], yi = cb[irow * 3 + 1], zi = cb[irow * 3 + 2];

    char* shbase = (char*)lds + SH_OFF + wave * 2048;

    for (int t = 0; t < 2; ++t) {
        const int j = jh * 512 + t * 256 + wave * 64 + lane;

        // ---- spherical harmonics (per-lane pair: (irow, j)) ----
        // Reference's two-step normalize == rel/||rel|| (zero stays zero).
        const float xj = cb[j * 3 + 0], yj = cb[j * 3 + 1], zj = cb[j * 3 + 2];
        const float rx = xi - xj, ry = yi - yj, rz = zi - zj;
        const float n2 = rx * rx + ry * ry + rz * rz;
        const float inv = (n2 > 0.f) ? __builtin_amdgcn_rsqf(n2) : 0.f;
        const float x = rx * inv, y = ry * inv, z = rz * inv;

        f32x4 s0, s1;         // sh[1..4], sh[5..8]  (sh[0]=C0 folded into bias1)
        s0.x = C1_F * x; s0.y = C1_F * y; s0.z = C1_F * z; s0.w = C2S3 * x * z;
        s1.x = C2S3 * x * y;
        s1.y = C2_F * (y * y - 0.5f * (x * x + z * z));
        s1.z = C2S3 * y * z;
        s1.w = C2H3 * (z * z - x * x);

        // store sh as f16 (B-frag-ready): row stride 24B, two b64 writes
        {
            uint2v uA = __builtin_bit_cast(uint2v, cvt4(s0));
            uint2v uB = __builtin_bit_cast(uint2v, cvt4(s1));
            *(uint2v*)(shbase + lane * 24)     = uA;
            *(uint2v*)(shbase + lane * 24 + 8) = uB;
        }
        __syncthreads();   // t=0: covers const-copy too; also orders sh write->read

        // ---- layer 1 (fused silu+pack into layer-2 B-frags) ----
        // h1^T[ch][pair] = W1^T . sh^T + b1'  (K=16, k>=8 zero in A)
        half4v a1[4]; f32x4 bias1[4];
        #pragma unroll
        for (int mi = 0; mi < 4; ++mi) {
            a1[mi]    = *(const half4v*)((char*)lds + W1_OFF + (mi * 64 + lane) * 8);
            bias1[mi] = *(const f32x4*)((char*)lds + B1P_OFF + (mi * 16 + 4 * g) * 4);
        }
        half4v b2f[4][4];      // layer-2 B-frags (32 VGPRs live)
        #pragma unroll
        for (int ni = 0; ni < 4; ++ni) {
            // B-frag: lane holds f16 sh[4(g&1)+1 .. +4] of pair ni*16+p (g>=2: A is zero)
            half4v bf = *(const half4v*)(shbase + (ni * 16 + p) * 24 + (g & 1) * 8);
            #pragma unroll
            for (int mi = 0; mi < 4; ++mi) {
                f32x4 acc = mfma16h(a1[mi], bf, bias1[mi]);
                b2f[mi][ni] = silucvt(acc);        // D1(mi,ni) -> B2-frag(ks=mi,ni)
            }
        }

        // ---- layer 2 with layer-3 accumulation fused into the mi loop ----
        half4v a3[4];
        #pragma unroll
        for (int ks = 0; ks < 4; ++ks)
            a3[ks] = *(const half4v*)((char*)lds + W3_OFF + (ks * 64 + lane) * 8);
        const f32x4 bias3v = *(const f32x4*)((char*)lds + B3P_OFF + 4 * g * 4);
        f32x4 acc3[4];
        #pragma unroll
        for (int ni = 0; ni < 4; ++ni) acc3[ni] = bias3v;

        #pragma unroll
        for (int mi = 0; mi < 4; ++mi) {
            half4v a2[4];
            #pragma unroll
            for (int ks = 0; ks < 4; ++ks)
                a2[ks] = *(const half4v*)((char*)lds + W2_OFF + ((mi * 4 + ks) * 64 + lane) * 8);
            const f32x4 bias2v = *(const f32x4*)((char*)lds + B2_OFF + (mi * 16 + 4 * g) * 4);
            #pragma unroll
            for (int ni = 0; ni < 4; ++ni) {
                f32x4 acc = bias2v;
                #pragma unroll
                for (int ks = 0; ks < 4; ++ks)
                    acc = mfma16h(a2[ks], b2f[ks][ni], acc);
                half4v b3 = silucvt(acc);          // D2(mi,ni) -> B3-frag(ks=mi,ni)
                acc3[ni] = mfma16h(a3[mi], b3, acc3[ni]);
            }
        }

        // ---- epilogue: transpose via LDS (reuse sh region) for coalesced 256B stores ----
        __syncthreads();   // wave done reading sh region (layer-1 input)
        if (g < 2) {
            #pragma unroll
            for (int ni = 0; ni < 4; ++ni) {
                #pragma unroll
                for (int i2 = 0; i2 < 4; ++i2)
                    *(float*)(shbase + (4 * g + i2) * 256 + (ni * 16 + p) * 4) = acc3[ni][i2];
            }
        }
        __syncthreads();
        #pragma unroll
        for (int s = 0; s < 8; ++s) {
            const float v = *(const float*)(shbase + s * 256 + lane * 4);
            out[((size_t)(b * 8 + s) << 20) + ((size_t)irow << 10) + j] = v;
        }
    }
}

extern "C" void kernel_launch(void* const* d_in, const int* in_sizes, int n_in,
                              void* d_out, int out_size, void* d_ws, size_t ws_size,
                              hipStream_t stream)
{
    const float* coords = (const float*)d_in[0];
    const float* w1 = (const float*)d_in[1];
    const float* b1 = (const float*)d_in[2];
    const float* w2 = (const float*)d_in[3];
    const float* b2 = (const float*)d_in[4];
    const float* w3 = (const float*)d_in[5];
    const float* b3 = (const float*)d_in[6];
    float* out = (float*)d_out;

    shab_stage<<<16, 256, 0, stream>>>(w1, b1, w2, b2, w3, b3, (unsigned char*)d_ws);

    const int B = in_sizes[0] / (S_TOK * 3);   // = 2
    shab_mfma<<<dim3(B * S_TOK * 2), 256, 0, stream>>>(coords, (const unsigned char*)d_ws, out);
}